// Round 9
// baseline (660.997 us; speedup 1.0000x reference)
//
#include <hip/hip_runtime.h>
#include <cstdint>
#include <cstddef>

// Problem constants (fixed by the reference)
#define NATOMS 400000
#define NEDGES 1600000
#define NGRAPH 4096
#define F_INN  78
#define HDIM   128
#define FF0D   256
#define FF1D   128

// layer-0 packed-input row: 78 feats + pad, bf16, 80 slots (160B)
#define XPAD   80

typedef __attribute__((ext_vector_type(8))) short short8;   // 8 bf16 (4 VGPRs)
typedef __attribute__((ext_vector_type(4))) short short4v;  // 4 bf16 (8B store)
typedef __attribute__((ext_vector_type(4))) float f32x4;
typedef __attribute__((ext_vector_type(2))) float f32x2;

// f32 -> bf16 round-to-nearest-even (bit-level)
static __device__ __forceinline__ short f2bf(float f) {
    unsigned u = __builtin_bit_cast(unsigned, f);
    unsigned r = (u + 0x7fffu + ((u >> 16) & 1u)) >> 16;
    return (short)r;
}
static __device__ __forceinline__ float bf2f(unsigned short u) {
    return __builtin_bit_cast(float, ((unsigned)u) << 16);
}

// ---------------- degree + per-edge rank (atomic return value) ----------------
__global__ __launch_bounds__(256) void k_degi(const int* __restrict__ dst,
                                              int* __restrict__ deg,
                                              int* __restrict__ rank, int E) {
    int e = blockIdx.x * 256 + threadIdx.x;
    if (e < E) rank[e] = atomicAdd(&deg[dst[e]], 1);
}

// ---------------- exclusive scan over N ints (3 kernels, in-place) ----------------
// scan1 also emits dinv = rsqrt(deg+1) (deg still intact at entry)
__global__ __launch_bounds__(256) void k_scan1(int* __restrict__ data,
                                               int* __restrict__ blockSums,
                                               float* __restrict__ dinv, int n) {
    __shared__ int ts[256];
    const int base = blockIdx.x * 1024 + threadIdx.x * 4;
    int v[4];
    #pragma unroll
    for (int j = 0; j < 4; ++j) v[j] = (base + j < n) ? data[base + j] : 0;
    #pragma unroll
    for (int j = 0; j < 4; ++j)
        if (base + j < n) dinv[base + j] = rsqrtf((float)v[j] + 1.0f);
    const int tot = v[0] + v[1] + v[2] + v[3];
    ts[threadIdx.x] = tot;
    __syncthreads();
    #pragma unroll
    for (int off = 1; off < 256; off <<= 1) {
        int t = (threadIdx.x >= off) ? ts[threadIdx.x - off] : 0;
        __syncthreads();
        ts[threadIdx.x] += t;
        __syncthreads();
    }
    int run = ts[threadIdx.x] - tot;
    #pragma unroll
    for (int j = 0; j < 4; ++j) {
        if (base + j < n) data[base + j] = run;
        run += v[j];
    }
    if (threadIdx.x == 255) blockSums[blockIdx.x] = ts[255];
}

__global__ __launch_bounds__(512) void k_scan2(int* __restrict__ blockSums, int nb) {
    __shared__ int ts[512];
    int v = (threadIdx.x < nb) ? blockSums[threadIdx.x] : 0;
    ts[threadIdx.x] = v;
    __syncthreads();
    #pragma unroll
    for (int off = 1; off < 512; off <<= 1) {
        int t = (threadIdx.x >= off) ? ts[threadIdx.x - off] : 0;
        __syncthreads();
        ts[threadIdx.x] += t;
        __syncthreads();
    }
    if (threadIdx.x < nb) blockSums[threadIdx.x] = ts[threadIdx.x] - v;
}

__global__ __launch_bounds__(256) void k_scan3(int* __restrict__ data,
                                               const int* __restrict__ blockSums,
                                               int n, int total) {
    const int off = blockSums[blockIdx.x];
    const int base = blockIdx.x * 1024 + threadIdx.x * 4;
    #pragma unroll
    for (int j = 0; j < 4; ++j)
        if (base + j < n) data[base + j] += off;
    if (blockIdx.x == 0 && threadIdx.x == 0) data[n] = total;
}

// ---------------- CSR fill: atomic-free (pos = row_start[d] + rank[e]) ----------
__global__ __launch_bounds__(256) void k_fill(const int* __restrict__ src,
                                              const int* __restrict__ dst,
                                              const int* __restrict__ row_start,
                                              const int* __restrict__ rank,
                                              int2* __restrict__ csr_ev,
                                              const float* __restrict__ dinv, int E) {
    int e = blockIdx.x * 256 + threadIdx.x;
    if (e >= E) return;
    int d = dst[e];
    int s = src[e];
    int pos = row_start[d] + rank[e];
    float norm = dinv[s] * dinv[d];
    csr_ev[pos] = make_int2(s, __builtin_bit_cast(int, norm));
}

// ---------------- weight pack: W [KSRC][128] f32 -> MFMA A-fragment order bf16 ----
// A[feat][k]: lane&15 = feat-within-tile ct, k = kc*32 + (lane>>4)*8 + j
// If BIASROW: k == KSRC takes bias[n] (input rows carry constant 1.0 there).
template<int KC, int KSRC, bool BIASROW>
__global__ __launch_bounds__(64) void k_packw(const float* __restrict__ W,
                                              const float* __restrict__ b,
                                              short* __restrict__ wf) {
    int t = blockIdx.x * 64 + threadIdx.x;      // t = f*64 + lane
    int f = t >> 6, lane = t & 63;
    int ct = f / KC, kc = f % KC;
    int n  = ct * 16 + (lane & 15);
    int k0 = kc * 32 + (lane >> 4) * 8;
    short8 o;
    #pragma unroll
    for (int j = 0; j < 8; ++j) {
        int k = k0 + j;
        float v = 0.f;
        if (k < KSRC) v = W[(size_t)k * 128 + n];
        else if (BIASROW && k == KSRC) v = b[n];
        o[j] = f2bf(v);
    }
    *(short8*)(wf + (size_t)t * 8) = o;
}

// ---------------- x pack: [N][78] f32 -> [N][80] bf16 (slots 78,79 zero) --------
__global__ __launch_bounds__(256) void k_packx(const float* __restrict__ x,
                                               unsigned short* __restrict__ xb) {
    int t = blockIdx.x * 256 + threadIdx.x;     // N*20 tasks, 4 shorts each
    if (t >= NATOMS * 20) return;
    int n = t / 20, g = t % 20;
    const float* xr = x + (size_t)n * F_INN + g * 4;
    short4v o;
    if (g < 19) {
        f32x2 a = *(const f32x2*)(xr);
        f32x2 b = *(const f32x2*)(xr + 2);
        o.x = f2bf(a.x); o.y = f2bf(a.y); o.z = f2bf(b.x); o.w = f2bf(b.y);
    } else {                                    // feats 76,77 + two zero pads
        f32x2 a = *(const f32x2*)(xr);
        o.x = f2bf(a.x); o.y = f2bf(a.y); o.z = 0; o.w = 0;
    }
    *(short4v*)(xb + (size_t)n * XPAD + g * 4) = o;
}

// ---------------- FUSED layer 0: gather-aggregate (78-dim) + MFMA GEMM ----------
// One block = 32 nodes, 256 threads. Output aggB = relu((A_hat x)@W0 + b0).
__global__ __launch_bounds__(256) void k_fused0(
    const unsigned short* __restrict__ xb, const short* __restrict__ wfrag,
    const int* __restrict__ row_start, const int2* __restrict__ csr_ev,
    const float* __restrict__ dinv, short* __restrict__ outp)
{
    constexpr int XLDS = 104;                          // shorts per xs row (208B)
    __shared__ __align__(16) short lds_w[24 * 64 * 8];       // 24 KB W0 fragments
    __shared__ __align__(16) unsigned short xs[32 * XLDS];   // 6.5 KB
    __shared__ __align__(16) char lds_st[4 * 2048];          // 8 KB store tiles

    const int tid = threadIdx.x;
    // ---- stage W0 fragments (L2-hot broadcast) ----
    #pragma unroll
    for (int it = 0; it < 6; ++it) {
        int t = it * 256 + tid;
        *(short8*)(lds_w + (size_t)t * 8) = *(const short8*)(wfrag + (size_t)t * 8);
    }

    // ---- phase 1: gather-aggregate 32 nodes into xs ----
    {
        const int nl = tid >> 3;               // local node 0..31
        const int n  = blockIdx.x * 32 + nl;
        const int l  = tid & 7;
        const int c8 = l * 8;                  // head feats c8..c8+7
        const int ct = 64 + l * 2;             // tail feats ct, ct+1
        const float dv = dinv[n];
        const float d2 = dv * dv;

        float acc[8], tacc0, tacc1;
        {
            const short8 sv = *(const short8*)(xb + (size_t)n * XPAD + c8);
            const unsigned tv = *(const unsigned*)(xb + (size_t)n * XPAD + ct);
            #pragma unroll
            for (int j = 0; j < 8; ++j) acc[j] = bf2f((unsigned short)sv[j]) * d2;
            tacc0 = bf2f((unsigned short)(tv & 0xffff)) * d2;
            tacc1 = bf2f((unsigned short)(tv >> 16)) * d2;
        }

        const int s0 = row_start[n], s1 = row_start[n + 1];
        int i = s0;
        for (; i + 3 < s1; i += 4) {
            const int2 e0 = csr_ev[i];
            const int2 e1 = csr_ev[i + 1];
            const int2 e2 = csr_ev[i + 2];
            const int2 e3 = csr_ev[i + 3];
            const short8 r0 = *(const short8*)(xb + (size_t)e0.x * XPAD + c8);
            const short8 r1 = *(const short8*)(xb + (size_t)e1.x * XPAD + c8);
            const short8 r2 = *(const short8*)(xb + (size_t)e2.x * XPAD + c8);
            const short8 r3 = *(const short8*)(xb + (size_t)e3.x * XPAD + c8);
            const unsigned t0 = *(const unsigned*)(xb + (size_t)e0.x * XPAD + ct);
            const unsigned t1 = *(const unsigned*)(xb + (size_t)e1.x * XPAD + ct);
            const unsigned t2 = *(const unsigned*)(xb + (size_t)e2.x * XPAD + ct);
            const unsigned t3 = *(const unsigned*)(xb + (size_t)e3.x * XPAD + ct);
            const float w0 = __builtin_bit_cast(float, e0.y);
            const float w1 = __builtin_bit_cast(float, e1.y);
            const float w2 = __builtin_bit_cast(float, e2.y);
            const float w3 = __builtin_bit_cast(float, e3.y);
            #pragma unroll
            for (int j = 0; j < 8; ++j) acc[j] = fmaf(bf2f((unsigned short)r0[j]), w0, acc[j]);
            #pragma unroll
            for (int j = 0; j < 8; ++j) acc[j] = fmaf(bf2f((unsigned short)r1[j]), w1, acc[j]);
            #pragma unroll
            for (int j = 0; j < 8; ++j) acc[j] = fmaf(bf2f((unsigned short)r2[j]), w2, acc[j]);
            #pragma unroll
            for (int j = 0; j < 8; ++j) acc[j] = fmaf(bf2f((unsigned short)r3[j]), w3, acc[j]);
            tacc0 = fmaf(bf2f((unsigned short)(t0 & 0xffff)), w0, tacc0);
            tacc1 = fmaf(bf2f((unsigned short)(t0 >> 16)),    w0, tacc1);
            tacc0 = fmaf(bf2f((unsigned short)(t1 & 0xffff)), w1, tacc0);
            tacc1 = fmaf(bf2f((unsigned short)(t1 >> 16)),    w1, tacc1);
            tacc0 = fmaf(bf2f((unsigned short)(t2 & 0xffff)), w2, tacc0);
            tacc1 = fmaf(bf2f((unsigned short)(t2 >> 16)),    w2, tacc1);
            tacc0 = fmaf(bf2f((unsigned short)(t3 & 0xffff)), w3, tacc0);
            tacc1 = fmaf(bf2f((unsigned short)(t3 >> 16)),    w3, tacc1);
        }
        for (; i < s1; ++i) {
            const int2 e0 = csr_ev[i];
            const short8 r0 = *(const short8*)(xb + (size_t)e0.x * XPAD + c8);
            const unsigned t0 = *(const unsigned*)(xb + (size_t)e0.x * XPAD + ct);
            const float w0 = __builtin_bit_cast(float, e0.y);
            #pragma unroll
            for (int j = 0; j < 8; ++j) acc[j] = fmaf(bf2f((unsigned short)r0[j]), w0, acc[j]);
            tacc0 = fmaf(bf2f((unsigned short)(t0 & 0xffff)), w0, tacc0);
            tacc1 = fmaf(bf2f((unsigned short)(t0 >> 16)),    w0, tacc1);
        }

        short8 o;
        #pragma unroll
        for (int j = 0; j < 8; ++j) o[j] = f2bf(acc[j]);
        *(short8*)(xs + nl * XLDS + c8) = o;
        unsigned to;
        if (l == 7) to = 0x00003F80u;      // slot78 = bf16(1.0), slot79 = 0
        else {
            to = (unsigned)(unsigned short)f2bf(tacc0) |
                 ((unsigned)(unsigned short)f2bf(tacc1) << 16);
        }
        *(unsigned*)(xs + nl * XLDS + ct) = to;
        *(unsigned*)(xs + nl * XLDS + 80 + l * 2) = 0u;   // zero k=80..95 (kc=2 tail)
    }
    __syncthreads();

    // ---- phase 2: MFMA ----
    const int lane = tid & 63;
    const int wid  = tid >> 6;
    const int m = lane & 15, q = lane >> 4;
    const int T  = wid >> 1;               // 16-node tile 0/1
    const int c0 = (wid & 1) * 4;          // ct half

    short8 afr[3];
    #pragma unroll
    for (int kc = 0; kc < 3; ++kc)
        afr[kc] = *(const short8*)(xs + (T * 16 + m) * XLDS + kc * 32 + q * 8);

    f32x4 acc[4];
    #pragma unroll
    for (int cc = 0; cc < 4; ++cc) acc[cc] = (f32x4){0.f, 0.f, 0.f, 0.f};
    #pragma unroll
    for (int kc = 0; kc < 3; ++kc)
        #pragma unroll
        for (int cc = 0; cc < 4; ++cc) {
            const short8 wv = *(const short8*)(lds_w + ((size_t)(((c0 + cc) * 3 + kc) * 64 + lane)) * 8);
            acc[cc] = __builtin_amdgcn_mfma_f32_16x16x32_bf16(wv, afr[kc], acc[cc], 0, 0, 0);
        }

    // relu + bf16, wave-private swizzled store tile, then 2x 1KB bursts
    char* const st = lds_st + wid * 2048;
    #pragma unroll
    for (int cc = 0; cc < 4; ++cc) {
        short4v o;
        o.x = f2bf(fmaxf(acc[cc][0], 0.f));
        o.y = f2bf(fmaxf(acc[cc][1], 0.f));
        o.z = f2bf(fmaxf(acc[cc][2], 0.f));
        o.w = f2bf(fmaxf(acc[cc][3], 0.f));
        const int c = (cc * 32 + q * 8) ^ ((m & 7) << 4);
        *(short4v*)(st + m * 128 + c) = o;
    }
    #pragma unroll
    for (int p = 0; p < 2; ++p) {
        const int r  = p * 8 + (lane >> 3);
        const int cb = ((lane & 7) * 16) ^ ((r & 7) << 4);
        const short8 v = *(const short8*)(st + r * 128 + cb);
        *(short8*)(outp + (size_t)(blockIdx.x * 32 + T * 16 + r) * 128
                        + c0 * 16 + (lane & 7) * 8) = v;
    }
}

// ---------------- FUSED layer 1: K-SPLIT gather (2x64 feats) + MFMA + pool ------
// One block = 64 nodes, 512 threads (8 waves). Reassociated A_hat(H@W1) =
// (A_hat H)@W1 with the gather K-SPLIT into two 64-feature phases so the
// random-read hot set is 51.2 MB per phase (one 128B line per edge row) ->
// L3-resident. Partial MFMA (kc = half*2..half*2+1) after each phase into a
// persistent accumulator; csr_ev is walked twice (L2-warm 2nd pass).
// Barrier before the phase-1 xs store (not before its global loads) so gather
// latency overlaps other waves' phase-0 MFMAs.
__global__ __launch_bounds__(512) void k_fused1(
    const unsigned short* __restrict__ hw, const short* __restrict__ wfrag,
    const int* __restrict__ row_start, const int2* __restrict__ csr_ev,
    const float* __restrict__ dinv, const float* __restrict__ bias,
    const int* __restrict__ batch, int* __restrict__ pool)
{
    constexpr int XL = 72;                             // 64 feats + 8 pad (144B)
    __shared__ __align__(16) short lds_w[32 * 64 * 8];       // 32 KB W1 fragments
    __shared__ __align__(16) unsigned short xs[64 * XL];     // 9.2 KB

    const int tid = threadIdx.x;
    // ---- stage W1 fragments ----
    #pragma unroll
    for (int it = 0; it < 4; ++it) {
        int t = it * 512 + tid;
        *(short8*)(lds_w + (size_t)t * 8) = *(const short8*)(wfrag + (size_t)t * 8);
    }

    const int nl = tid >> 3;               // local node 0..63
    const int n  = blockIdx.x * 64 + nl;
    const int l  = tid & 7;
    const float dv = dinv[n];
    const float d2 = dv * dv;
    const int s0 = row_start[n], s1 = row_start[n + 1];

    const int lane = tid & 63;
    const int wid  = tid >> 6;             // 0..7
    const int m = lane & 15, q = lane >> 4;
    const int T  = wid >> 1;               // node tile 0..3
    const int c0 = (wid & 1) * 4;          // ct half (4 ct each)

    f32x4 acc[4];
    #pragma unroll
    for (int cc = 0; cc < 4; ++cc) acc[cc] = (f32x4){0.f, 0.f, 0.f, 0.f};

    #pragma unroll
    for (int half = 0; half < 2; ++half) {
        const int cb = half * 64 + l * 8;  // this lane's 8 feats within the half

        // ---- gather phase: 8 feats/lane over this node's edges ----
        float a[8];
        {
            const short8 sv = *(const short8*)(hw + (size_t)n * HDIM + cb);
            #pragma unroll
            for (int j = 0; j < 8; ++j) a[j] = bf2f((unsigned short)sv[j]) * d2;
        }
        int i = s0;
        for (; i + 3 < s1; i += 4) {
            const int2 e0 = csr_ev[i];
            const int2 e1 = csr_ev[i + 1];
            const int2 e2 = csr_ev[i + 2];
            const int2 e3 = csr_ev[i + 3];
            const short8 r0 = *(const short8*)(hw + (size_t)e0.x * HDIM + cb);
            const short8 r1 = *(const short8*)(hw + (size_t)e1.x * HDIM + cb);
            const short8 r2 = *(const short8*)(hw + (size_t)e2.x * HDIM + cb);
            const short8 r3 = *(const short8*)(hw + (size_t)e3.x * HDIM + cb);
            const float w0 = __builtin_bit_cast(float, e0.y);
            const float w1 = __builtin_bit_cast(float, e1.y);
            const float w2 = __builtin_bit_cast(float, e2.y);
            const float w3 = __builtin_bit_cast(float, e3.y);
            #pragma unroll
            for (int j = 0; j < 8; ++j) a[j] = fmaf(bf2f((unsigned short)r0[j]), w0, a[j]);
            #pragma unroll
            for (int j = 0; j < 8; ++j) a[j] = fmaf(bf2f((unsigned short)r1[j]), w1, a[j]);
            #pragma unroll
            for (int j = 0; j < 8; ++j) a[j] = fmaf(bf2f((unsigned short)r2[j]), w2, a[j]);
            #pragma unroll
            for (int j = 0; j < 8; ++j) a[j] = fmaf(bf2f((unsigned short)r3[j]), w3, a[j]);
        }
        for (; i < s1; ++i) {
            const int2 e0 = csr_ev[i];
            const short8 r0 = *(const short8*)(hw + (size_t)e0.x * HDIM + cb);
            const float w0 = __builtin_bit_cast(float, e0.y);
            #pragma unroll
            for (int j = 0; j < 8; ++j) a[j] = fmaf(bf2f((unsigned short)r0[j]), w0, a[j]);
        }

        short8 o;
        #pragma unroll
        for (int j = 0; j < 8; ++j) o[j] = f2bf(a[j]);

        if (half == 1) __syncthreads();    // all phase-0 xs reads done before overwrite
        *(short8*)(xs + nl * XL + l * 8) = o;
        __syncthreads();                   // xs (and, first time, lds_w) visible

        // ---- partial MFMA: global kc = half*2 + kc2 ----
        #pragma unroll
        for (int kc2 = 0; kc2 < 2; ++kc2) {
            const short8 afr = *(const short8*)(xs + (T * 16 + m) * XL + kc2 * 32 + q * 8);
            #pragma unroll
            for (int cc = 0; cc < 4; ++cc) {
                const short8 wv = *(const short8*)(lds_w +
                    ((size_t)(((c0 + cc) * 4 + half * 2 + kc2) * 64 + lane)) * 8);
                acc[cc] = __builtin_amdgcn_mfma_f32_16x16x32_bf16(wv, afr, acc[cc], 0, 0, 0);
            }
        }
    }

    // ---- epilogue: bias + relu + per-graph max over nodes + atomicMax ----
    const int nb    = blockIdx.x * 64;
    const int gbase = batch[nb];                       // uniform
    const int glast = batch[nb + 63];                  // uniform
    const int idx   = batch[nb + T * 16 + m] - gbase;  // 0 or 1

    float v[16];
    #pragma unroll
    for (int cc = 0; cc < 4; ++cc) {
        const f32x4 b4 = *(const f32x4*)(bias + (c0 + cc) * 16 + q * 4);
        #pragma unroll
        for (int j = 0; j < 4; ++j)
            v[cc * 4 + j] = fmaxf(acc[cc][j] + b4[j], 0.f);
    }

    // slot 0 (graph gbase)
    {
        float r[16];
        #pragma unroll
        for (int k = 0; k < 16; ++k) r[k] = (idx == 0) ? v[k] : 0.f;
        #pragma unroll
        for (int msk = 1; msk <= 8; msk <<= 1)
            #pragma unroll
            for (int k = 0; k < 16; ++k)
                r[k] = fmaxf(r[k], __shfl_xor(r[k], msk));
        if (m == 0) {
            #pragma unroll
            for (int cc = 0; cc < 4; ++cc)
                #pragma unroll
                for (int j = 0; j < 4; ++j)
                    atomicMax(pool + (size_t)gbase * HDIM + (c0 + cc) * 16 + q * 4 + j,
                              __builtin_bit_cast(int, r[cc * 4 + j]));
        }
    }
    // slot 1 (graph gbase+1), only for boundary blocks
    if (glast != gbase) {
        float r[16];
        #pragma unroll
        for (int k = 0; k < 16; ++k) r[k] = (idx == 1) ? v[k] : 0.f;
        #pragma unroll
        for (int msk = 1; msk <= 8; msk <<= 1)
            #pragma unroll
            for (int k = 0; k < 16; ++k)
                r[k] = fmaxf(r[k], __shfl_xor(r[k], msk));
        if (m == 0) {
            #pragma unroll
            for (int cc = 0; cc < 4; ++cc)
                #pragma unroll
                for (int j = 0; j < 4; ++j)
                    atomicMax(pool + (size_t)(gbase + 1) * HDIM + (c0 + cc) * 16 + q * 4 + j,
                              __builtin_bit_cast(int, r[cc * 4 + j]));
        }
    }
}

// ---------------- f32 register-blocked GEMM (FF head only, tiny) ----------------
template<int K, int NC, bool OUT_RELU_BIAS>
__global__ __launch_bounds__(256) void k_gemm(
    const float* __restrict__ in, const float* __restrict__ W,
    const float* __restrict__ out_bias, float* __restrict__ out0, int M)
{
    constexpr int BK = 32;
    constexpr int TC = NC / 8;
    constexpr int TR = 256 / TC;
    constexpr int ROWS = TR * 8;
    constexpr int XST = ROWS + 4;

    __shared__ float xs[BK][XST];
    __shared__ float ws[BK][NC];

    const int tid = threadIdx.x;
    const int tc  = tid % TC;
    const int tr  = tid / TC;
    const int row0 = blockIdx.x * ROWS;

    float acc[8][8];
    #pragma unroll
    for (int i = 0; i < 8; ++i)
        #pragma unroll
        for (int j = 0; j < 8; ++j) acc[i][j] = 0.f;

    for (int k0 = 0; k0 < K; k0 += BK) {
        {
            constexpr int TASKS = BK * NC / 4;
            #pragma unroll
            for (int it = 0; it < TASKS / 256; ++it) {
                int t  = it * 256 + tid;
                int wk = t / (NC / 4);
                int wc = (t % (NC / 4)) * 4;
                *(float4*)(&ws[wk][wc]) = *(const float4*)(W + (size_t)(k0 + wk) * NC + wc);
            }
        }
        {
            constexpr int TASKS = ROWS * BK / 4;
            #pragma unroll
            for (int it = 0; it < TASKS / 256; ++it) {
                int t   = it * 256 + tid;
                int r   = t / (BK / 4);
                int kq  = (t % (BK / 4)) * 4;
                float4 x4 = *(const float4*)(in + (size_t)(row0 + r) * K + k0 + kq);
                xs[kq + 0][r] = x4.x; xs[kq + 1][r] = x4.y;
                xs[kq + 2][r] = x4.z; xs[kq + 3][r] = x4.w;
            }
        }
        __syncthreads();
        #pragma unroll 8
        for (int kk = 0; kk < BK; ++kk) {
            float a[8], b[8];
            #pragma unroll
            for (int i = 0; i < 8; ++i) a[i] = xs[kk][tr * 8 + i];
            #pragma unroll
            for (int j = 0; j < 8; ++j) b[j] = ws[kk][tc * 8 + j];
            #pragma unroll
            for (int i = 0; i < 8; ++i)
                #pragma unroll
                for (int j = 0; j < 8; ++j)
                    acc[i][j] = fmaf(a[i], b[j], acc[i][j]);
        }
        __syncthreads();
    }

    #pragma unroll
    for (int i = 0; i < 8; ++i) {
        const int row = row0 + tr * 8 + i;
        #pragma unroll
        for (int jq = 0; jq < 2; ++jq) {
            const int col = tc * 8 + jq * 4;
            float4 v;
            v.x = acc[i][jq * 4 + 0]; v.y = acc[i][jq * 4 + 1];
            v.z = acc[i][jq * 4 + 2]; v.w = acc[i][jq * 4 + 3];
            if constexpr (OUT_RELU_BIAS) {
                const float4 bb = *(const float4*)(out_bias + col);
                v.x = fmaxf(v.x + bb.x, 0.f); v.y = fmaxf(v.y + bb.y, 0.f);
                v.z = fmaxf(v.z + bb.z, 0.f); v.w = fmaxf(v.w + bb.w, 0.f);
            }
            *(float4*)(out0 + (size_t)row * NC + col) = v;
        }
    }
}

extern "C" void kernel_launch(void* const* d_in, const int* in_sizes, int n_in,
                              void* d_out, int out_size, void* d_ws, size_t ws_size,
                              hipStream_t stream) {
    const float* x    = (const float*)d_in[0];
    const int*   ei   = (const int*)d_in[1];
    const int*   batch= (const int*)d_in[2];
    const float* W0   = (const float*)d_in[3];
    const float* b0   = (const float*)d_in[4];
    const float* W1   = (const float*)d_in[5];
    const float* b1   = (const float*)d_in[6];
    const float* Wf0  = (const float*)d_in[7];
    const float* bf0  = (const float*)d_in[8];
    const float* Wf1  = (const float*)d_in[9];
    const float* bf1  = (const float*)d_in[10];
    float* out = (float*)d_out;

    const int* srcI = ei;
    const int* dstI = ei + NEDGES;

    constexpr int SCAN_NBLK = (NATOMS + 1023) / 1024;   // 391

    // workspace layout — ~291.2 MB (ws is ~499 MB per measured poison fill).
    //   rank aliases base+0 (dead after k_fill; nothing else lives there now
    //   that hwA is eliminated).
    char* base = (char*)d_ws;
    int*   rank      = (int*)(base + 0);                             // E ints
    unsigned short* aggB = (unsigned short*)(base + 102400000);      // N*128 bf16
    float* dinv      = (float*)(base + 204800000);                   // N f32
    int*   row_start = (int*)(base + 206400000);                     // N+1 ints
    int2*  csr_ev    = (int2*)(base + 208000064);                    // E int2
    int*   blockSums = (int*)(base + 220800064);                     // 512 ints
    float* pool      = (float*)(base + 220802112);                   // G*128 f32
    float* ff0       = (float*)(base + 222899264);                   // G*256 f32
    short* wf0       = (short*)(base + 227093568);                   // 24,576 B
    short* wf1       = (short*)(base + 227118144);                   // 32,768 B
    unsigned short* xb = (unsigned short*)(base + 227150912);        // N*80 bf16 = 64 MB

    // 1) degree (+rank) -> scan (+dinv) -> atomic-free CSR fill
    hipMemsetAsync(row_start, 0, (size_t)(NATOMS + 1) * sizeof(int), stream);
    hipMemsetAsync(pool, 0, (size_t)NGRAPH * HDIM * sizeof(float), stream);  // relu identity
    k_degi<<<(NEDGES + 255) / 256, 256, 0, stream>>>(dstI, row_start, rank, NEDGES);
    k_scan1<<<SCAN_NBLK, 256, 0, stream>>>(row_start, blockSums, dinv, NATOMS);
    k_scan2<<<1, 512, 0, stream>>>(blockSums, SCAN_NBLK);
    k_scan3<<<SCAN_NBLK, 256, 0, stream>>>(row_start, blockSums, NATOMS, NEDGES);
    k_fill<<<(NEDGES + 255) / 256, 256, 0, stream>>>(srcI, dstI, row_start, rank,
                                                     csr_ev, dinv, NEDGES);

    // 2) pack weights (W0 augmented: k=78 row carries b0) + pack x to bf16[80]
    k_packw<3, F_INN, true><<<8 * 3, 64, 0, stream>>>(W0, b0, wf0);
    k_packw<4, HDIM, false><<<8 * 4, 64, 0, stream>>>(W1, nullptr, wf1);
    k_packx<<<(NATOMS * 20 + 255) / 256, 256, 0, stream>>>(x, xb);

    // 3) layer 0 FUSED: gather(78-dim) + GEMM + bias(slot78) + relu -> aggB
    k_fused0<<<NATOMS / 32, 256, 0, stream>>>(xb, wf0, row_start, csr_ev, dinv,
                                              (short*)aggB);

    // 4) layer 1 FUSED (K-split): 2x 64-feat gather phases + partial MFMA + pool
    k_fused1<<<NATOMS / 64, 512, 0, stream>>>(aggB, wf1, row_start, csr_ev,
                                              dinv, b1, batch, (int*)pool);

    // 5) FF head (f32, tiny)
    k_gemm<HDIM, FF0D, true><<<NGRAPH / 64, 256, 0, stream>>>(pool, Wf0, bf0, ff0, NGRAPH);
    k_gemm<FF0D, FF1D, true><<<NGRAPH / 128, 256, 0, stream>>>(ff0, Wf1, bf1, out, NGRAPH);
}

// Round 10
// 648.164 us; speedup vs baseline: 1.0198x; 1.0198x over previous
//
#include <hip/hip_runtime.h>
#include <cstdint>
#include <cstddef>

// Problem constants (fixed by the reference)
#define NATOMS 400000
#define NEDGES 1600000
#define NGRAPH 4096
#define F_INN  78
#define HDIM   128
#define FF0D   256
#define FF1D   128

typedef __attribute__((ext_vector_type(8))) short short8;   // 8 bf16 (4 VGPRs)
typedef __attribute__((ext_vector_type(4))) short short4v;  // 4 bf16 (8B store)
typedef __attribute__((ext_vector_type(4))) float f32x4;
typedef __attribute__((ext_vector_type(2))) float f32x2;

// f32 -> bf16 round-to-nearest-even (bit-level)
static __device__ __forceinline__ short f2bf(float f) {
    unsigned u = __builtin_bit_cast(unsigned, f);
    unsigned r = (u + 0x7fffu + ((u >> 16) & 1u)) >> 16;
    return (short)r;
}
static __device__ __forceinline__ float bf2f(unsigned short u) {
    return __builtin_bit_cast(float, ((unsigned)u) << 16);
}

// ---------------- degree + per-edge rank (atomic return value) ----------------
__global__ __launch_bounds__(256) void k_degi(const int* __restrict__ dst,
                                              int* __restrict__ deg,
                                              int* __restrict__ rank, int E) {
    int e = blockIdx.x * 256 + threadIdx.x;
    if (e < E) rank[e] = atomicAdd(&deg[dst[e]], 1);
}

// ---------------- exclusive scan over N ints (3 kernels, in-place) ----------------
// scan1 also emits dinv = rsqrt(deg+1) (deg still intact at entry)
__global__ __launch_bounds__(256) void k_scan1(int* __restrict__ data,
                                               int* __restrict__ blockSums,
                                               float* __restrict__ dinv, int n) {
    __shared__ int ts[256];
    const int base = blockIdx.x * 1024 + threadIdx.x * 4;
    int v[4];
    #pragma unroll
    for (int j = 0; j < 4; ++j) v[j] = (base + j < n) ? data[base + j] : 0;
    #pragma unroll
    for (int j = 0; j < 4; ++j)
        if (base + j < n) dinv[base + j] = rsqrtf((float)v[j] + 1.0f);
    const int tot = v[0] + v[1] + v[2] + v[3];
    ts[threadIdx.x] = tot;
    __syncthreads();
    #pragma unroll
    for (int off = 1; off < 256; off <<= 1) {
        int t = (threadIdx.x >= off) ? ts[threadIdx.x - off] : 0;
        __syncthreads();
        ts[threadIdx.x] += t;
        __syncthreads();
    }
    int run = ts[threadIdx.x] - tot;
    #pragma unroll
    for (int j = 0; j < 4; ++j) {
        if (base + j < n) data[base + j] = run;
        run += v[j];
    }
    if (threadIdx.x == 255) blockSums[blockIdx.x] = ts[255];
}

__global__ __launch_bounds__(512) void k_scan2(int* __restrict__ blockSums, int nb) {
    __shared__ int ts[512];
    int v = (threadIdx.x < nb) ? blockSums[threadIdx.x] : 0;
    ts[threadIdx.x] = v;
    __syncthreads();
    #pragma unroll
    for (int off = 1; off < 512; off <<= 1) {
        int t = (threadIdx.x >= off) ? ts[threadIdx.x - off] : 0;
        __syncthreads();
        ts[threadIdx.x] += t;
        __syncthreads();
    }
    if (threadIdx.x < nb) blockSums[threadIdx.x] = ts[threadIdx.x] - v;
}

__global__ __launch_bounds__(256) void k_scan3(int* __restrict__ data,
                                               const int* __restrict__ blockSums,
                                               int n, int total) {
    const int off = blockSums[blockIdx.x];
    const int base = blockIdx.x * 1024 + threadIdx.x * 4;
    #pragma unroll
    for (int j = 0; j < 4; ++j)
        if (base + j < n) data[base + j] += off;
    if (blockIdx.x == 0 && threadIdx.x == 0) data[n] = total;
}

// ---------------- CSR fill: atomic-free (pos = row_start[d] + rank[e]) ----------
__global__ __launch_bounds__(256) void k_fill(const int* __restrict__ src,
                                              const int* __restrict__ dst,
                                              const int* __restrict__ row_start,
                                              const int* __restrict__ rank,
                                              int2* __restrict__ csr_ev,
                                              const float* __restrict__ dinv, int E) {
    int e = blockIdx.x * 256 + threadIdx.x;
    if (e >= E) return;
    int d = dst[e];
    int s = src[e];
    int pos = row_start[d] + rank[e];
    float norm = dinv[s] * dinv[d];
    csr_ev[pos] = make_int2(s, __builtin_bit_cast(int, norm));
}

// ---------------- weight pack: W [KSRC][128] f32 -> MFMA A-fragment order bf16 ----
// A[feat][k]: lane&15 = feat-within-tile ct, k = kc*32 + (lane>>4)*8 + j
// If BIASROW: k == KSRC takes bias[n] (input rows carry constant 1.0 there).
template<int KC, int KSRC, bool BIASROW>
__global__ __launch_bounds__(64) void k_packw(const float* __restrict__ W,
                                              const float* __restrict__ b,
                                              short* __restrict__ wf) {
    int t = blockIdx.x * 64 + threadIdx.x;      // t = f*64 + lane
    int f = t >> 6, lane = t & 63;
    int ct = f / KC, kc = f % KC;
    int n  = ct * 16 + (lane & 15);
    int k0 = kc * 32 + (lane >> 4) * 8;
    short8 o;
    #pragma unroll
    for (int j = 0; j < 8; ++j) {
        int k = k0 + j;
        float v = 0.f;
        if (k < KSRC) v = W[(size_t)k * 128 + n];
        else if (BIASROW && k == KSRC) v = b[n];
        o[j] = f2bf(v);
    }
    *(short8*)(wf + (size_t)t * 8) = o;
}

// ---------------- x pack: [N][78] f32 -> SPLIT layout ---------------------------
// xh [N][64] bf16: feats 0..63, 128B rows, 128B-ALIGNED (one cache line per
//   random edge read, 100% utilized).
// xt [N][16] bf16: feats 64..77 + 2 zero pads, 32B rows (12.8 MB region stays
//   L2/L3-hot under the gather).
// The old [N][80] (160B-stride) layout straddled 2-3 lines per random row read.
__global__ __launch_bounds__(256) void k_packx(const float* __restrict__ x,
                                               unsigned short* __restrict__ xh,
                                               unsigned short* __restrict__ xt) {
    int t = blockIdx.x * 256 + threadIdx.x;     // N*10 tasks, 8 shorts each
    if (t >= NATOMS * 10) return;
    int n = t / 10, g = t % 10;
    short8 o;
    if (g < 9) {                                // feats g*8 .. g*8+7
        const float* xr = x + (size_t)n * F_INN + g * 8;
        #pragma unroll
        for (int p = 0; p < 4; ++p) {
            f32x2 a = *(const f32x2*)(xr + 2 * p);
            o[2 * p] = f2bf(a.x); o[2 * p + 1] = f2bf(a.y);
        }
    } else {                                    // feats 72..77 + two zero pads
        const float* xr = x + (size_t)n * F_INN + 72;
        #pragma unroll
        for (int p = 0; p < 3; ++p) {
            f32x2 a = *(const f32x2*)(xr + 2 * p);
            o[2 * p] = f2bf(a.x); o[2 * p + 1] = f2bf(a.y);
        }
        o[6] = 0; o[7] = 0;
    }
    if (g < 8)       *(short8*)(xh + (size_t)n * 64 + g * 8) = o;
    else if (g == 8) *(short8*)(xt + (size_t)n * 16) = o;
    else             *(short8*)(xt + (size_t)n * 16 + 8) = o;
}

// ---------------- FUSED layer 0: gather-aggregate (78-dim) + MFMA GEMM ----------
// One block = 32 nodes, 256 threads. Output aggB = relu((A_hat x)@W0 + b0).
// Reads the SPLIT xh/xt layout: head = one aligned 128B line per edge row,
// tail = 4B from the hot 12.8MB xt region.
__global__ __launch_bounds__(256) void k_fused0(
    const unsigned short* __restrict__ xh, const unsigned short* __restrict__ xt,
    const short* __restrict__ wfrag,
    const int* __restrict__ row_start, const int2* __restrict__ csr_ev,
    const float* __restrict__ dinv, short* __restrict__ outp)
{
    constexpr int XLDS = 104;                          // shorts per xs row (208B)
    __shared__ __align__(16) short lds_w[24 * 64 * 8];       // 24 KB W0 fragments
    __shared__ __align__(16) unsigned short xs[32 * XLDS];   // 6.5 KB
    __shared__ __align__(16) char lds_st[4 * 2048];          // 8 KB store tiles

    const int tid = threadIdx.x;
    // ---- stage W0 fragments (L2-hot broadcast) ----
    #pragma unroll
    for (int it = 0; it < 6; ++it) {
        int t = it * 256 + tid;
        *(short8*)(lds_w + (size_t)t * 8) = *(const short8*)(wfrag + (size_t)t * 8);
    }

    // ---- phase 1: gather-aggregate 32 nodes into xs ----
    {
        const int nl = tid >> 3;               // local node 0..31
        const int n  = blockIdx.x * 32 + nl;
        const int l  = tid & 7;
        const int c8 = l * 8;                  // head feats c8..c8+7
        const int ct = 64 + l * 2;             // tail feats ct, ct+1 (xs slot)
        const float dv = dinv[n];
        const float d2 = dv * dv;

        float acc[8], tacc0, tacc1;
        {
            const short8 sv = *(const short8*)(xh + (size_t)n * 64 + c8);
            const unsigned tv = *(const unsigned*)(xt + (size_t)n * 16 + l * 2);
            #pragma unroll
            for (int j = 0; j < 8; ++j) acc[j] = bf2f((unsigned short)sv[j]) * d2;
            tacc0 = bf2f((unsigned short)(tv & 0xffff)) * d2;
            tacc1 = bf2f((unsigned short)(tv >> 16)) * d2;
        }

        const int s0 = row_start[n], s1 = row_start[n + 1];
        int i = s0;
        for (; i + 3 < s1; i += 4) {
            const int2 e0 = csr_ev[i];
            const int2 e1 = csr_ev[i + 1];
            const int2 e2 = csr_ev[i + 2];
            const int2 e3 = csr_ev[i + 3];
            const short8 r0 = *(const short8*)(xh + (size_t)e0.x * 64 + c8);
            const short8 r1 = *(const short8*)(xh + (size_t)e1.x * 64 + c8);
            const short8 r2 = *(const short8*)(xh + (size_t)e2.x * 64 + c8);
            const short8 r3 = *(const short8*)(xh + (size_t)e3.x * 64 + c8);
            const unsigned t0 = *(const unsigned*)(xt + (size_t)e0.x * 16 + l * 2);
            const unsigned t1 = *(const unsigned*)(xt + (size_t)e1.x * 16 + l * 2);
            const unsigned t2 = *(const unsigned*)(xt + (size_t)e2.x * 16 + l * 2);
            const unsigned t3 = *(const unsigned*)(xt + (size_t)e3.x * 16 + l * 2);
            const float w0 = __builtin_bit_cast(float, e0.y);
            const float w1 = __builtin_bit_cast(float, e1.y);
            const float w2 = __builtin_bit_cast(float, e2.y);
            const float w3 = __builtin_bit_cast(float, e3.y);
            #pragma unroll
            for (int j = 0; j < 8; ++j) acc[j] = fmaf(bf2f((unsigned short)r0[j]), w0, acc[j]);
            #pragma unroll
            for (int j = 0; j < 8; ++j) acc[j] = fmaf(bf2f((unsigned short)r1[j]), w1, acc[j]);
            #pragma unroll
            for (int j = 0; j < 8; ++j) acc[j] = fmaf(bf2f((unsigned short)r2[j]), w2, acc[j]);
            #pragma unroll
            for (int j = 0; j < 8; ++j) acc[j] = fmaf(bf2f((unsigned short)r3[j]), w3, acc[j]);
            tacc0 = fmaf(bf2f((unsigned short)(t0 & 0xffff)), w0, tacc0);
            tacc1 = fmaf(bf2f((unsigned short)(t0 >> 16)),    w0, tacc1);
            tacc0 = fmaf(bf2f((unsigned short)(t1 & 0xffff)), w1, tacc0);
            tacc1 = fmaf(bf2f((unsigned short)(t1 >> 16)),    w1, tacc1);
            tacc0 = fmaf(bf2f((unsigned short)(t2 & 0xffff)), w2, tacc0);
            tacc1 = fmaf(bf2f((unsigned short)(t2 >> 16)),    w2, tacc1);
            tacc0 = fmaf(bf2f((unsigned short)(t3 & 0xffff)), w3, tacc0);
            tacc1 = fmaf(bf2f((unsigned short)(t3 >> 16)),    w3, tacc1);
        }
        for (; i < s1; ++i) {
            const int2 e0 = csr_ev[i];
            const short8 r0 = *(const short8*)(xh + (size_t)e0.x * 64 + c8);
            const unsigned t0 = *(const unsigned*)(xt + (size_t)e0.x * 16 + l * 2);
            const float w0 = __builtin_bit_cast(float, e0.y);
            #pragma unroll
            for (int j = 0; j < 8; ++j) acc[j] = fmaf(bf2f((unsigned short)r0[j]), w0, acc[j]);
            tacc0 = fmaf(bf2f((unsigned short)(t0 & 0xffff)), w0, tacc0);
            tacc1 = fmaf(bf2f((unsigned short)(t0 >> 16)),    w0, tacc1);
        }

        short8 o;
        #pragma unroll
        for (int j = 0; j < 8; ++j) o[j] = f2bf(acc[j]);
        *(short8*)(xs + nl * XLDS + c8) = o;
        unsigned to;
        if (l == 7) to = 0x00003F80u;      // slot78 = bf16(1.0), slot79 = 0
        else {
            to = (unsigned)(unsigned short)f2bf(tacc0) |
                 ((unsigned)(unsigned short)f2bf(tacc1) << 16);
        }
        *(unsigned*)(xs + nl * XLDS + ct) = to;
        *(unsigned*)(xs + nl * XLDS + 80 + l * 2) = 0u;   // zero k=80..95 (kc=2 tail)
    }
    __syncthreads();

    // ---- phase 2: MFMA ----
    const int lane = tid & 63;
    const int wid  = tid >> 6;
    const int m = lane & 15, q = lane >> 4;
    const int T  = wid >> 1;               // 16-node tile 0/1
    const int c0 = (wid & 1) * 4;          // ct half

    short8 afr[3];
    #pragma unroll
    for (int kc = 0; kc < 3; ++kc)
        afr[kc] = *(const short8*)(xs + (T * 16 + m) * XLDS + kc * 32 + q * 8);

    f32x4 acc[4];
    #pragma unroll
    for (int cc = 0; cc < 4; ++cc) acc[cc] = (f32x4){0.f, 0.f, 0.f, 0.f};
    #pragma unroll
    for (int kc = 0; kc < 3; ++kc)
        #pragma unroll
        for (int cc = 0; cc < 4; ++cc) {
            const short8 wv = *(const short8*)(lds_w + ((size_t)(((c0 + cc) * 3 + kc) * 64 + lane)) * 8);
            acc[cc] = __builtin_amdgcn_mfma_f32_16x16x32_bf16(wv, afr[kc], acc[cc], 0, 0, 0);
        }

    // relu + bf16, wave-private swizzled store tile, then 2x 1KB bursts
    char* const st = lds_st + wid * 2048;
    #pragma unroll
    for (int cc = 0; cc < 4; ++cc) {
        short4v o;
        o.x = f2bf(fmaxf(acc[cc][0], 0.f));
        o.y = f2bf(fmaxf(acc[cc][1], 0.f));
        o.z = f2bf(fmaxf(acc[cc][2], 0.f));
        o.w = f2bf(fmaxf(acc[cc][3], 0.f));
        const int c = (cc * 32 + q * 8) ^ ((m & 7) << 4);
        *(short4v*)(st + m * 128 + c) = o;
    }
    #pragma unroll
    for (int p = 0; p < 2; ++p) {
        const int r  = p * 8 + (lane >> 3);
        const int cb = ((lane & 7) * 16) ^ ((r & 7) << 4);
        const short8 v = *(const short8*)(st + r * 128 + cb);
        *(short8*)(outp + (size_t)(blockIdx.x * 32 + T * 16 + r) * 128
                        + c0 * 16 + (lane & 7) * 8) = v;
    }
}

// ---------------- FUSED layer 1: gather (128-dim) + MFMA + bias + relu + POOL ----
// One block = 64 nodes, 512 threads (8 waves). (R8 form — the R9 K-split
// regressed: FETCH unchanged, csr walked twice. Full-width single pass.)
__global__ __launch_bounds__(512) void k_fused1(
    const unsigned short* __restrict__ hw, const short* __restrict__ wfrag,
    const int* __restrict__ row_start, const int2* __restrict__ csr_ev,
    const float* __restrict__ dinv, const float* __restrict__ bias,
    const int* __restrict__ batch, int* __restrict__ pool)
{
    constexpr int XL = 136;                            // shorts per xs row (272B)
    __shared__ __align__(16) short lds_w[32 * 64 * 8];       // 32 KB W1 fragments
    __shared__ __align__(16) unsigned short xs[64 * XL];     // 17.4 KB

    const int tid = threadIdx.x;
    // ---- stage W1 fragments ----
    #pragma unroll
    for (int it = 0; it < 4; ++it) {
        int t = it * 512 + tid;
        *(short8*)(lds_w + (size_t)t * 8) = *(const short8*)(wfrag + (size_t)t * 8);
    }

    // ---- phase 1: gather-aggregate 64 nodes (full 128 feats) into xs ----
    {
        const int nl = tid >> 3;               // local node 0..63
        const int n  = blockIdx.x * 64 + nl;
        const int l  = tid & 7;
        const int cA = l * 8;                  // feats cA..cA+7
        const int cB = 64 + l * 8;             // feats cB..cB+7
        const float dv = dinv[n];
        const float d2 = dv * dv;

        float aA[8], aB[8];
        {
            const short8 sa = *(const short8*)(hw + (size_t)n * HDIM + cA);
            const short8 sb = *(const short8*)(hw + (size_t)n * HDIM + cB);
            #pragma unroll
            for (int j = 0; j < 8; ++j) {
                aA[j] = bf2f((unsigned short)sa[j]) * d2;
                aB[j] = bf2f((unsigned short)sb[j]) * d2;
            }
        }

        const int s0 = row_start[n], s1 = row_start[n + 1];
        int i = s0;
        for (; i + 1 < s1; i += 2) {
            const int2 e0 = csr_ev[i];
            const int2 e1 = csr_ev[i + 1];
            const short8 rA0 = *(const short8*)(hw + (size_t)e0.x * HDIM + cA);
            const short8 rB0 = *(const short8*)(hw + (size_t)e0.x * HDIM + cB);
            const short8 rA1 = *(const short8*)(hw + (size_t)e1.x * HDIM + cA);
            const short8 rB1 = *(const short8*)(hw + (size_t)e1.x * HDIM + cB);
            const float w0 = __builtin_bit_cast(float, e0.y);
            const float w1 = __builtin_bit_cast(float, e1.y);
            #pragma unroll
            for (int j = 0; j < 8; ++j) {
                aA[j] = fmaf(bf2f((unsigned short)rA0[j]), w0, aA[j]);
                aB[j] = fmaf(bf2f((unsigned short)rB0[j]), w0, aB[j]);
            }
            #pragma unroll
            for (int j = 0; j < 8; ++j) {
                aA[j] = fmaf(bf2f((unsigned short)rA1[j]), w1, aA[j]);
                aB[j] = fmaf(bf2f((unsigned short)rB1[j]), w1, aB[j]);
            }
        }
        for (; i < s1; ++i) {
            const int2 e0 = csr_ev[i];
            const short8 rA0 = *(const short8*)(hw + (size_t)e0.x * HDIM + cA);
            const short8 rB0 = *(const short8*)(hw + (size_t)e0.x * HDIM + cB);
            const float w0 = __builtin_bit_cast(float, e0.y);
            #pragma unroll
            for (int j = 0; j < 8; ++j) {
                aA[j] = fmaf(bf2f((unsigned short)rA0[j]), w0, aA[j]);
                aB[j] = fmaf(bf2f((unsigned short)rB0[j]), w0, aB[j]);
            }
        }

        short8 oA, oB;
        #pragma unroll
        for (int j = 0; j < 8; ++j) { oA[j] = f2bf(aA[j]); oB[j] = f2bf(aB[j]); }
        *(short8*)(xs + nl * XL + cA) = oA;
        *(short8*)(xs + nl * XL + cB) = oB;
    }
    __syncthreads();

    // ---- phase 2: MFMA (4 node-tiles x 2 ct-halves across 8 waves) ----
    const int lane = tid & 63;
    const int wid  = tid >> 6;             // 0..7
    const int m = lane & 15, q = lane >> 4;
    const int T  = wid >> 1;               // node tile 0..3
    const int c0 = (wid & 1) * 4;          // ct half (4 ct each)

    short8 afr[4];
    #pragma unroll
    for (int kc = 0; kc < 4; ++kc)
        afr[kc] = *(const short8*)(xs + (T * 16 + m) * XL + kc * 32 + q * 8);

    f32x4 acc[4];
    #pragma unroll
    for (int cc = 0; cc < 4; ++cc) acc[cc] = (f32x4){0.f, 0.f, 0.f, 0.f};
    #pragma unroll
    for (int kc = 0; kc < 4; ++kc)
        #pragma unroll
        for (int cc = 0; cc < 4; ++cc) {
            const short8 wv = *(const short8*)(lds_w + ((size_t)(((c0 + cc) * 4 + kc) * 64 + lane)) * 8);
            acc[cc] = __builtin_amdgcn_mfma_f32_16x16x32_bf16(wv, afr[kc], acc[cc], 0, 0, 0);
        }

    // ---- epilogue: bias + relu + per-graph max over nodes + atomicMax ----
    const int nb    = blockIdx.x * 64;
    const int gbase = batch[nb];                       // uniform
    const int glast = batch[nb + 63];                  // uniform
    const int idx   = batch[nb + T * 16 + m] - gbase;  // 0 or 1

    float v[16];
    #pragma unroll
    for (int cc = 0; cc < 4; ++cc) {
        const f32x4 b4 = *(const f32x4*)(bias + (c0 + cc) * 16 + q * 4);
        #pragma unroll
        for (int j = 0; j < 4; ++j)
            v[cc * 4 + j] = fmaxf(acc[cc][j] + b4[j], 0.f);
    }

    // slot 0 (graph gbase)
    {
        float r[16];
        #pragma unroll
        for (int k = 0; k < 16; ++k) r[k] = (idx == 0) ? v[k] : 0.f;
        #pragma unroll
        for (int msk = 1; msk <= 8; msk <<= 1)
            #pragma unroll
            for (int k = 0; k < 16; ++k)
                r[k] = fmaxf(r[k], __shfl_xor(r[k], msk));
        if (m == 0) {
            #pragma unroll
            for (int cc = 0; cc < 4; ++cc)
                #pragma unroll
                for (int j = 0; j < 4; ++j)
                    atomicMax(pool + (size_t)gbase * HDIM + (c0 + cc) * 16 + q * 4 + j,
                              __builtin_bit_cast(int, r[cc * 4 + j]));
        }
    }
    // slot 1 (graph gbase+1), only for boundary blocks
    if (glast != gbase) {
        float r[16];
        #pragma unroll
        for (int k = 0; k < 16; ++k) r[k] = (idx == 1) ? v[k] : 0.f;
        #pragma unroll
        for (int msk = 1; msk <= 8; msk <<= 1)
            #pragma unroll
            for (int k = 0; k < 16; ++k)
                r[k] = fmaxf(r[k], __shfl_xor(r[k], msk));
        if (m == 0) {
            #pragma unroll
            for (int cc = 0; cc < 4; ++cc)
                #pragma unroll
                for (int j = 0; j < 4; ++j)
                    atomicMax(pool + (size_t)(gbase + 1) * HDIM + (c0 + cc) * 16 + q * 4 + j,
                              __builtin_bit_cast(int, r[cc * 4 + j]));
        }
    }
}

// ---------------- f32 register-blocked GEMM (FF head only, tiny) ----------------
template<int K, int NC, bool OUT_RELU_BIAS>
__global__ __launch_bounds__(256) void k_gemm(
    const float* __restrict__ in, const float* __restrict__ W,
    const float* __restrict__ out_bias, float* __restrict__ out0, int M)
{
    constexpr int BK = 32;
    constexpr int TC = NC / 8;
    constexpr int TR = 256 / TC;
    constexpr int ROWS = TR * 8;
    constexpr int XST = ROWS + 4;

    __shared__ float xs[BK][XST];
    __shared__ float ws[BK][NC];

    const int tid = threadIdx.x;
    const int tc  = tid % TC;
    const int tr  = tid / TC;
    const int row0 = blockIdx.x * ROWS;

    float acc[8][8];
    #pragma unroll
    for (int i = 0; i < 8; ++i)
        #pragma unroll
        for (int j = 0; j < 8; ++j) acc[i][j] = 0.f;

    for (int k0 = 0; k0 < K; k0 += BK) {
        {
            constexpr int TASKS = BK * NC / 4;
            #pragma unroll
            for (int it = 0; it < TASKS / 256; ++it) {
                int t  = it * 256 + tid;
                int wk = t / (NC / 4);
                int wc = (t % (NC / 4)) * 4;
                *(float4*)(&ws[wk][wc]) = *(const float4*)(W + (size_t)(k0 + wk) * NC + wc);
            }
        }
        {
            constexpr int TASKS = ROWS * BK / 4;
            #pragma unroll
            for (int it = 0; it < TASKS / 256; ++it) {
                int t   = it * 256 + tid;
                int r   = t / (BK / 4);
                int kq  = (t % (BK / 4)) * 4;
                float4 x4 = *(const float4*)(in + (size_t)(row0 + r) * K + k0 + kq);
                xs[kq + 0][r] = x4.x; xs[kq + 1][r] = x4.y;
                xs[kq + 2][r] = x4.z; xs[kq + 3][r] = x4.w;
            }
        }
        __syncthreads();
        #pragma unroll 8
        for (int kk = 0; kk < BK; ++kk) {
            float a[8], b[8];
            #pragma unroll
            for (int i = 0; i < 8; ++i) a[i] = xs[kk][tr * 8 + i];
            #pragma unroll
            for (int j = 0; j < 8; ++j) b[j] = ws[kk][tc * 8 + j];
            #pragma unroll
            for (int i = 0; i < 8; ++i)
                #pragma unroll
                for (int j = 0; j < 8; ++j)
                    acc[i][j] = fmaf(a[i], b[j], acc[i][j]);
        }
        __syncthreads();
    }

    #pragma unroll
    for (int i = 0; i < 8; ++i) {
        const int row = row0 + tr * 8 + i;
        #pragma unroll
        for (int jq = 0; jq < 2; ++jq) {
            const int col = tc * 8 + jq * 4;
            float4 v;
            v.x = acc[i][jq * 4 + 0]; v.y = acc[i][jq * 4 + 1];
            v.z = acc[i][jq * 4 + 2]; v.w = acc[i][jq * 4 + 3];
            if constexpr (OUT_RELU_BIAS) {
                const float4 bb = *(const float4*)(out_bias + col);
                v.x = fmaxf(v.x + bb.x, 0.f); v.y = fmaxf(v.y + bb.y, 0.f);
                v.z = fmaxf(v.z + bb.z, 0.f); v.w = fmaxf(v.w + bb.w, 0.f);
            }
            *(float4*)(out0 + (size_t)row * NC + col) = v;
        }
    }
}

extern "C" void kernel_launch(void* const* d_in, const int* in_sizes, int n_in,
                              void* d_out, int out_size, void* d_ws, size_t ws_size,
                              hipStream_t stream) {
    const float* x    = (const float*)d_in[0];
    const int*   ei   = (const int*)d_in[1];
    const int*   batch= (const int*)d_in[2];
    const float* W0   = (const float*)d_in[3];
    const float* b0   = (const float*)d_in[4];
    const float* W1   = (const float*)d_in[5];
    const float* b1   = (const float*)d_in[6];
    const float* Wf0  = (const float*)d_in[7];
    const float* bf0  = (const float*)d_in[8];
    const float* Wf1  = (const float*)d_in[9];
    const float* bf1  = (const float*)d_in[10];
    float* out = (float*)d_out;

    const int* srcI = ei;
    const int* dstI = ei + NEDGES;

    constexpr int SCAN_NBLK = (NATOMS + 1023) / 1024;   // 391

    // workspace layout — ~293 MB (ws is ~499 MB per measured poison fill).
    //   rank aliases base+0 (dead after k_fill).
    //   xh at base+228000000 (128B-aligned rows!), xt at base+280000000.
    char* base = (char*)d_ws;
    int*   rank      = (int*)(base + 0);                             // E ints
    unsigned short* aggB = (unsigned short*)(base + 102400000);      // N*128 bf16
    float* dinv      = (float*)(base + 204800000);                   // N f32
    int*   row_start = (int*)(base + 206400000);                     // N+1 ints
    int2*  csr_ev    = (int2*)(base + 208000064);                    // E int2
    int*   blockSums = (int*)(base + 220800064);                     // 512 ints
    float* pool      = (float*)(base + 220802112);                   // G*128 f32
    float* ff0       = (float*)(base + 222899264);                   // G*256 f32
    short* wf0       = (short*)(base + 227093568);                   // 24,576 B
    short* wf1       = (short*)(base + 227118144);                   // 32,768 B
    unsigned short* xh = (unsigned short*)(base + 228000000);        // N*64 bf16 = 51.2 MB (128B-aligned)
    unsigned short* xt = (unsigned short*)(base + 280000000);        // N*16 bf16 = 12.8 MB

    // 1) degree (+rank) -> scan (+dinv) -> atomic-free CSR fill
    hipMemsetAsync(row_start, 0, (size_t)(NATOMS + 1) * sizeof(int), stream);
    hipMemsetAsync(pool, 0, (size_t)NGRAPH * HDIM * sizeof(float), stream);  // relu identity
    k_degi<<<(NEDGES + 255) / 256, 256, 0, stream>>>(dstI, row_start, rank, NEDGES);
    k_scan1<<<SCAN_NBLK, 256, 0, stream>>>(row_start, blockSums, dinv, NATOMS);
    k_scan2<<<1, 512, 0, stream>>>(blockSums, SCAN_NBLK);
    k_scan3<<<SCAN_NBLK, 256, 0, stream>>>(row_start, blockSums, NATOMS, NEDGES);
    k_fill<<<(NEDGES + 255) / 256, 256, 0, stream>>>(srcI, dstI, row_start, rank,
                                                     csr_ev, dinv, NEDGES);

    // 2) pack weights (W0 augmented: k=78 row carries b0) + pack x to split bf16
    k_packw<3, F_INN, true><<<8 * 3, 64, 0, stream>>>(W0, b0, wf0);
    k_packw<4, HDIM, false><<<8 * 4, 64, 0, stream>>>(W1, nullptr, wf1);
    k_packx<<<(NATOMS * 10 + 255) / 256, 256, 0, stream>>>(x, xh, xt);

    // 3) layer 0 FUSED: gather(78-dim, split layout) + GEMM + bias + relu -> aggB
    k_fused0<<<NATOMS / 32, 256, 0, stream>>>(xh, xt, wf0, row_start, csr_ev, dinv,
                                              (short*)aggB);

    // 4) layer 1 FUSED: gather(128-dim over aggB) + GEMM + b1 + relu + max-pool
    k_fused1<<<NATOMS / 64, 512, 0, stream>>>(aggB, wf1, row_start, csr_ev,
                                              dinv, b1, batch, (int*)pool);

    // 5) FF head (f32, tiny)
    k_gemm<HDIM, FF0D, true><<<NGRAPH / 64, 256, 0, stream>>>(pool, Wf0, bf0, ff0, NGRAPH);
    k_gemm<FF0D, FF1D, true><<<NGRAPH / 128, 256, 0, stream>>>(ff0, Wf1, bf1, out, NGRAPH);
}

// Round 11
// 643.921 us; speedup vs baseline: 1.0265x; 1.0066x over previous
//
#include <hip/hip_runtime.h>
#include <cstdint>
#include <cstddef>

// Problem constants (fixed by the reference)
#define NATOMS 400000
#define NEDGES 1600000
#define NGRAPH 4096
#define F_INN  78
#define HDIM   128
#define FF0D   256
#define FF1D   128

typedef __attribute__((ext_vector_type(8))) short short8;   // 8 bf16 (4 VGPRs)
typedef __attribute__((ext_vector_type(4))) short short4v;  // 4 bf16 (8B store)
typedef __attribute__((ext_vector_type(4))) float f32x4;
typedef __attribute__((ext_vector_type(2))) float f32x2;

// f32 -> bf16 round-to-nearest-even (bit-level)
static __device__ __forceinline__ short f2bf(float f) {
    unsigned u = __builtin_bit_cast(unsigned, f);
    unsigned r = (u + 0x7fffu + ((u >> 16) & 1u)) >> 16;
    return (short)r;
}
static __device__ __forceinline__ float bf2f(unsigned short u) {
    return __builtin_bit_cast(float, ((unsigned)u) << 16);
}

// ---------------- degree + per-edge rank (atomic return value) ----------------
__global__ __launch_bounds__(256) void k_degi(const int* __restrict__ dst,
                                              int* __restrict__ deg,
                                              int* __restrict__ rank, int E) {
    int e = blockIdx.x * 256 + threadIdx.x;
    if (e < E) rank[e] = atomicAdd(&deg[dst[e]], 1);
}

// ---------------- exclusive scan over N ints (3 kernels, in-place) ----------------
// scan1 also emits dinv = rsqrt(deg+1) (deg still intact at entry)
__global__ __launch_bounds__(256) void k_scan1(int* __restrict__ data,
                                               int* __restrict__ blockSums,
                                               float* __restrict__ dinv, int n) {
    __shared__ int ts[256];
    const int base = blockIdx.x * 1024 + threadIdx.x * 4;
    int v[4];
    #pragma unroll
    for (int j = 0; j < 4; ++j) v[j] = (base + j < n) ? data[base + j] : 0;
    #pragma unroll
    for (int j = 0; j < 4; ++j)
        if (base + j < n) dinv[base + j] = rsqrtf((float)v[j] + 1.0f);
    const int tot = v[0] + v[1] + v[2] + v[3];
    ts[threadIdx.x] = tot;
    __syncthreads();
    #pragma unroll
    for (int off = 1; off < 256; off <<= 1) {
        int t = (threadIdx.x >= off) ? ts[threadIdx.x - off] : 0;
        __syncthreads();
        ts[threadIdx.x] += t;
        __syncthreads();
    }
    int run = ts[threadIdx.x] - tot;
    #pragma unroll
    for (int j = 0; j < 4; ++j) {
        if (base + j < n) data[base + j] = run;
        run += v[j];
    }
    if (threadIdx.x == 255) blockSums[blockIdx.x] = ts[255];
}

__global__ __launch_bounds__(512) void k_scan2(int* __restrict__ blockSums, int nb) {
    __shared__ int ts[512];
    int v = (threadIdx.x < nb) ? blockSums[threadIdx.x] : 0;
    ts[threadIdx.x] = v;
    __syncthreads();
    #pragma unroll
    for (int off = 1; off < 512; off <<= 1) {
        int t = (threadIdx.x >= off) ? ts[threadIdx.x - off] : 0;
        __syncthreads();
        ts[threadIdx.x] += t;
        __syncthreads();
    }
    if (threadIdx.x < nb) blockSums[threadIdx.x] = ts[threadIdx.x] - v;
}

__global__ __launch_bounds__(256) void k_scan3(int* __restrict__ data,
                                               const int* __restrict__ blockSums,
                                               int n, int total) {
    const int off = blockSums[blockIdx.x];
    const int base = blockIdx.x * 1024 + threadIdx.x * 4;
    #pragma unroll
    for (int j = 0; j < 4; ++j)
        if (base + j < n) data[base + j] += off;
    if (blockIdx.x == 0 && threadIdx.x == 0) data[n] = total;
}

// ---------------- CSR fill: atomic-free (pos = row_start[d] + rank[e]) ----------
__global__ __launch_bounds__(256) void k_fill(const int* __restrict__ src,
                                              const int* __restrict__ dst,
                                              const int* __restrict__ row_start,
                                              const int* __restrict__ rank,
                                              int2* __restrict__ csr_ev,
                                              const float* __restrict__ dinv, int E) {
    int e = blockIdx.x * 256 + threadIdx.x;
    if (e >= E) return;
    int d = dst[e];
    int s = src[e];
    int pos = row_start[d] + rank[e];
    float norm = dinv[s] * dinv[d];
    csr_ev[pos] = make_int2(s, __builtin_bit_cast(int, norm));
}

// ---------------- weight pack: W [KSRC][128] f32 -> MFMA A-fragment order bf16 ----
// A[feat][k]: lane&15 = feat-within-tile ct, k = kc*32 + (lane>>4)*8 + j
// If BIASROW: k == KSRC takes bias[n] (input rows carry constant 1.0 there).
template<int KC, int KSRC, bool BIASROW>
__global__ __launch_bounds__(64) void k_packw(const float* __restrict__ W,
                                              const float* __restrict__ b,
                                              short* __restrict__ wf) {
    int t = blockIdx.x * 64 + threadIdx.x;      // t = f*64 + lane
    int f = t >> 6, lane = t & 63;
    int ct = f / KC, kc = f % KC;
    int n  = ct * 16 + (lane & 15);
    int k0 = kc * 32 + (lane >> 4) * 8;
    short8 o;
    #pragma unroll
    for (int j = 0; j < 8; ++j) {
        int k = k0 + j;
        float v = 0.f;
        if (k < KSRC) v = W[(size_t)k * 128 + n];
        else if (BIASROW && k == KSRC) v = b[n];
        o[j] = f2bf(v);
    }
    *(short8*)(wf + (size_t)t * 8) = o;
}

// ---------------- x pack: [N][78] f32 -> SPLIT layout ---------------------------
// xh [N][64] bf16: feats 0..63, 128B-aligned rows (one cache line per random
//   edge read). xt [N][16] bf16: feats 64..77 + 2 zero pads (12.8 MB, L2/L3-hot).
__global__ __launch_bounds__(256) void k_packx(const float* __restrict__ x,
                                               unsigned short* __restrict__ xh,
                                               unsigned short* __restrict__ xt) {
    int t = blockIdx.x * 256 + threadIdx.x;     // N*10 tasks, 8 shorts each
    if (t >= NATOMS * 10) return;
    int n = t / 10, g = t % 10;
    short8 o;
    if (g < 9) {                                // feats g*8 .. g*8+7
        const float* xr = x + (size_t)n * F_INN + g * 8;
        #pragma unroll
        for (int p = 0; p < 4; ++p) {
            f32x2 a = *(const f32x2*)(xr + 2 * p);
            o[2 * p] = f2bf(a.x); o[2 * p + 1] = f2bf(a.y);
        }
    } else {                                    // feats 72..77 + two zero pads
        const float* xr = x + (size_t)n * F_INN + 72;
        #pragma unroll
        for (int p = 0; p < 3; ++p) {
            f32x2 a = *(const f32x2*)(xr + 2 * p);
            o[2 * p] = f2bf(a.x); o[2 * p + 1] = f2bf(a.y);
        }
        o[6] = 0; o[7] = 0;
    }
    if (g < 8)       *(short8*)(xh + (size_t)n * 64 + g * 8) = o;
    else if (g == 8) *(short8*)(xt + (size_t)n * 16) = o;
    else             *(short8*)(xt + (size_t)n * 16 + 8) = o;
}

// ---------------- FUSED layer 0: gather-aggregate (78-dim) + MFMA GEMM ----------
// One block = 32 nodes, 256 threads. Output aggB = relu((A_hat x)@W0 + b0).
// NO weight LDS staging: wv comes straight from global (24KB table, L2-resident
// broadcast) — LDS drops to 14.5KB -> 8 blocks/CU = 32 waves/CU (was 16),
// doubling latency-hiding for the random gather phase (R11 occupancy lever).
__global__ __launch_bounds__(256) void k_fused0(
    const unsigned short* __restrict__ xh, const unsigned short* __restrict__ xt,
    const short* __restrict__ wfrag,
    const int* __restrict__ row_start, const int2* __restrict__ csr_ev,
    const float* __restrict__ dinv, short* __restrict__ outp)
{
    constexpr int XLDS = 104;                          // shorts per xs row (208B)
    __shared__ __align__(16) unsigned short xs[32 * XLDS];   // 6.5 KB
    __shared__ __align__(16) char lds_st[4 * 2048];          // 8 KB store tiles

    const int tid = threadIdx.x;

    // ---- phase 1: gather-aggregate 32 nodes into xs ----
    {
        const int nl = tid >> 3;               // local node 0..31
        const int n  = blockIdx.x * 32 + nl;
        const int l  = tid & 7;
        const int c8 = l * 8;                  // head feats c8..c8+7
        const int ct = 64 + l * 2;             // tail feats ct, ct+1 (xs slot)
        const float dv = dinv[n];
        const float d2 = dv * dv;

        float acc[8], tacc0, tacc1;
        {
            const short8 sv = *(const short8*)(xh + (size_t)n * 64 + c8);
            const unsigned tv = *(const unsigned*)(xt + (size_t)n * 16 + l * 2);
            #pragma unroll
            for (int j = 0; j < 8; ++j) acc[j] = bf2f((unsigned short)sv[j]) * d2;
            tacc0 = bf2f((unsigned short)(tv & 0xffff)) * d2;
            tacc1 = bf2f((unsigned short)(tv >> 16)) * d2;
        }

        const int s0 = row_start[n], s1 = row_start[n + 1];
        int i = s0;
        for (; i + 3 < s1; i += 4) {
            const int2 e0 = csr_ev[i];
            const int2 e1 = csr_ev[i + 1];
            const int2 e2 = csr_ev[i + 2];
            const int2 e3 = csr_ev[i + 3];
            const short8 r0 = *(const short8*)(xh + (size_t)e0.x * 64 + c8);
            const short8 r1 = *(const short8*)(xh + (size_t)e1.x * 64 + c8);
            const short8 r2 = *(const short8*)(xh + (size_t)e2.x * 64 + c8);
            const short8 r3 = *(const short8*)(xh + (size_t)e3.x * 64 + c8);
            const unsigned t0 = *(const unsigned*)(xt + (size_t)e0.x * 16 + l * 2);
            const unsigned t1 = *(const unsigned*)(xt + (size_t)e1.x * 16 + l * 2);
            const unsigned t2 = *(const unsigned*)(xt + (size_t)e2.x * 16 + l * 2);
            const unsigned t3 = *(const unsigned*)(xt + (size_t)e3.x * 16 + l * 2);
            const float w0 = __builtin_bit_cast(float, e0.y);
            const float w1 = __builtin_bit_cast(float, e1.y);
            const float w2 = __builtin_bit_cast(float, e2.y);
            const float w3 = __builtin_bit_cast(float, e3.y);
            #pragma unroll
            for (int j = 0; j < 8; ++j) acc[j] = fmaf(bf2f((unsigned short)r0[j]), w0, acc[j]);
            #pragma unroll
            for (int j = 0; j < 8; ++j) acc[j] = fmaf(bf2f((unsigned short)r1[j]), w1, acc[j]);
            #pragma unroll
            for (int j = 0; j < 8; ++j) acc[j] = fmaf(bf2f((unsigned short)r2[j]), w2, acc[j]);
            #pragma unroll
            for (int j = 0; j < 8; ++j) acc[j] = fmaf(bf2f((unsigned short)r3[j]), w3, acc[j]);
            tacc0 = fmaf(bf2f((unsigned short)(t0 & 0xffff)), w0, tacc0);
            tacc1 = fmaf(bf2f((unsigned short)(t0 >> 16)),    w0, tacc1);
            tacc0 = fmaf(bf2f((unsigned short)(t1 & 0xffff)), w1, tacc0);
            tacc1 = fmaf(bf2f((unsigned short)(t1 >> 16)),    w1, tacc1);
            tacc0 = fmaf(bf2f((unsigned short)(t2 & 0xffff)), w2, tacc0);
            tacc1 = fmaf(bf2f((unsigned short)(t2 >> 16)),    w2, tacc1);
            tacc0 = fmaf(bf2f((unsigned short)(t3 & 0xffff)), w3, tacc0);
            tacc1 = fmaf(bf2f((unsigned short)(t3 >> 16)),    w3, tacc1);
        }
        for (; i < s1; ++i) {
            const int2 e0 = csr_ev[i];
            const short8 r0 = *(const short8*)(xh + (size_t)e0.x * 64 + c8);
            const unsigned t0 = *(const unsigned*)(xt + (size_t)e0.x * 16 + l * 2);
            const float w0 = __builtin_bit_cast(float, e0.y);
            #pragma unroll
            for (int j = 0; j < 8; ++j) acc[j] = fmaf(bf2f((unsigned short)r0[j]), w0, acc[j]);
            tacc0 = fmaf(bf2f((unsigned short)(t0 & 0xffff)), w0, tacc0);
            tacc1 = fmaf(bf2f((unsigned short)(t0 >> 16)),    w0, tacc1);
        }

        short8 o;
        #pragma unroll
        for (int j = 0; j < 8; ++j) o[j] = f2bf(acc[j]);
        *(short8*)(xs + nl * XLDS + c8) = o;
        unsigned to;
        if (l == 7) to = 0x00003F80u;      // slot78 = bf16(1.0), slot79 = 0
        else {
            to = (unsigned)(unsigned short)f2bf(tacc0) |
                 ((unsigned)(unsigned short)f2bf(tacc1) << 16);
        }
        *(unsigned*)(xs + nl * XLDS + ct) = to;
        *(unsigned*)(xs + nl * XLDS + 80 + l * 2) = 0u;   // zero k=80..95 (kc=2 tail)
    }
    __syncthreads();

    // ---- phase 2: MFMA (weights direct from global/L2) ----
    const int lane = tid & 63;
    const int wid  = tid >> 6;
    const int m = lane & 15, q = lane >> 4;
    const int T  = wid >> 1;               // 16-node tile 0/1
    const int c0 = (wid & 1) * 4;          // ct half

    short8 afr[3];
    #pragma unroll
    for (int kc = 0; kc < 3; ++kc)
        afr[kc] = *(const short8*)(xs + (T * 16 + m) * XLDS + kc * 32 + q * 8);

    f32x4 acc[4];
    #pragma unroll
    for (int cc = 0; cc < 4; ++cc) acc[cc] = (f32x4){0.f, 0.f, 0.f, 0.f};
    #pragma unroll
    for (int kc = 0; kc < 3; ++kc)
        #pragma unroll
        for (int cc = 0; cc < 4; ++cc) {
            const short8 wv = *(const short8*)(wfrag + ((size_t)(((c0 + cc) * 3 + kc) * 64 + lane)) * 8);
            acc[cc] = __builtin_amdgcn_mfma_f32_16x16x32_bf16(wv, afr[kc], acc[cc], 0, 0, 0);
        }

    // relu + bf16, wave-private swizzled store tile, then 2x 1KB bursts
    char* const st = lds_st + wid * 2048;
    #pragma unroll
    for (int cc = 0; cc < 4; ++cc) {
        short4v o;
        o.x = f2bf(fmaxf(acc[cc][0], 0.f));
        o.y = f2bf(fmaxf(acc[cc][1], 0.f));
        o.z = f2bf(fmaxf(acc[cc][2], 0.f));
        o.w = f2bf(fmaxf(acc[cc][3], 0.f));
        const int c = (cc * 32 + q * 8) ^ ((m & 7) << 4);
        *(short4v*)(st + m * 128 + c) = o;
    }
    #pragma unroll
    for (int p = 0; p < 2; ++p) {
        const int r  = p * 8 + (lane >> 3);
        const int cb = ((lane & 7) * 16) ^ ((r & 7) << 4);
        const short8 v = *(const short8*)(st + r * 128 + cb);
        *(short8*)(outp + (size_t)(blockIdx.x * 32 + T * 16 + r) * 128
                        + c0 * 16 + (lane & 7) * 8) = v;
    }
}

// ---------------- FUSED layer 1: gather (128-dim) + MFMA + bias + relu + POOL ----
// One block = 64 nodes, 512 threads (8 waves). NO weight LDS staging (32KB W1
// table read from global/L2 at MFMA time) — LDS drops 49 -> 17.4KB, so 4
// blocks/CU = 32 waves/CU (was 3 blocks/24 waves).
__global__ __launch_bounds__(512) void k_fused1(
    const unsigned short* __restrict__ hw, const short* __restrict__ wfrag,
    const int* __restrict__ row_start, const int2* __restrict__ csr_ev,
    const float* __restrict__ dinv, const float* __restrict__ bias,
    const int* __restrict__ batch, int* __restrict__ pool)
{
    constexpr int XL = 136;                            // shorts per xs row (272B)
    __shared__ __align__(16) unsigned short xs[64 * XL];     // 17.4 KB

    const int tid = threadIdx.x;

    // ---- phase 1: gather-aggregate 64 nodes (full 128 feats) into xs ----
    {
        const int nl = tid >> 3;               // local node 0..63
        const int n  = blockIdx.x * 64 + nl;
        const int l  = tid & 7;
        const int cA = l * 8;                  // feats cA..cA+7
        const int cB = 64 + l * 8;             // feats cB..cB+7
        const float dv = dinv[n];
        const float d2 = dv * dv;

        float aA[8], aB[8];
        {
            const short8 sa = *(const short8*)(hw + (size_t)n * HDIM + cA);
            const short8 sb = *(const short8*)(hw + (size_t)n * HDIM + cB);
            #pragma unroll
            for (int j = 0; j < 8; ++j) {
                aA[j] = bf2f((unsigned short)sa[j]) * d2;
                aB[j] = bf2f((unsigned short)sb[j]) * d2;
            }
        }

        const int s0 = row_start[n], s1 = row_start[n + 1];
        int i = s0;
        for (; i + 1 < s1; i += 2) {
            const int2 e0 = csr_ev[i];
            const int2 e1 = csr_ev[i + 1];
            const short8 rA0 = *(const short8*)(hw + (size_t)e0.x * HDIM + cA);
            const short8 rB0 = *(const short8*)(hw + (size_t)e0.x * HDIM + cB);
            const short8 rA1 = *(const short8*)(hw + (size_t)e1.x * HDIM + cA);
            const short8 rB1 = *(const short8*)(hw + (size_t)e1.x * HDIM + cB);
            const float w0 = __builtin_bit_cast(float, e0.y);
            const float w1 = __builtin_bit_cast(float, e1.y);
            #pragma unroll
            for (int j = 0; j < 8; ++j) {
                aA[j] = fmaf(bf2f((unsigned short)rA0[j]), w0, aA[j]);
                aB[j] = fmaf(bf2f((unsigned short)rB0[j]), w0, aB[j]);
            }
            #pragma unroll
            for (int j = 0; j < 8; ++j) {
                aA[j] = fmaf(bf2f((unsigned short)rA1[j]), w1, aA[j]);
                aB[j] = fmaf(bf2f((unsigned short)rB1[j]), w1, aB[j]);
            }
        }
        for (; i < s1; ++i) {
            const int2 e0 = csr_ev[i];
            const short8 rA0 = *(const short8*)(hw + (size_t)e0.x * HDIM + cA);
            const short8 rB0 = *(const short8*)(hw + (size_t)e0.x * HDIM + cB);
            const float w0 = __builtin_bit_cast(float, e0.y);
            #pragma unroll
            for (int j = 0; j < 8; ++j) {
                aA[j] = fmaf(bf2f((unsigned short)rA0[j]), w0, aA[j]);
                aB[j] = fmaf(bf2f((unsigned short)rB0[j]), w0, aB[j]);
            }
        }

        short8 oA, oB;
        #pragma unroll
        for (int j = 0; j < 8; ++j) { oA[j] = f2bf(aA[j]); oB[j] = f2bf(aB[j]); }
        *(short8*)(xs + nl * XL + cA) = oA;
        *(short8*)(xs + nl * XL + cB) = oB;
    }
    __syncthreads();

    // ---- phase 2: MFMA (weights direct from global/L2) ----
    const int lane = tid & 63;
    const int wid  = tid >> 6;             // 0..7
    const int m = lane & 15, q = lane >> 4;
    const int T  = wid >> 1;               // node tile 0..3
    const int c0 = (wid & 1) * 4;          // ct half (4 ct each)

    short8 afr[4];
    #pragma unroll
    for (int kc = 0; kc < 4; ++kc)
        afr[kc] = *(const short8*)(xs + (T * 16 + m) * XL + kc * 32 + q * 8);

    f32x4 acc[4];
    #pragma unroll
    for (int cc = 0; cc < 4; ++cc) acc[cc] = (f32x4){0.f, 0.f, 0.f, 0.f};
    #pragma unroll
    for (int kc = 0; kc < 4; ++kc)
        #pragma unroll
        for (int cc = 0; cc < 4; ++cc) {
            const short8 wv = *(const short8*)(wfrag + ((size_t)(((c0 + cc) * 4 + kc) * 64 + lane)) * 8);
            acc[cc] = __builtin_amdgcn_mfma_f32_16x16x32_bf16(wv, afr[kc], acc[cc], 0, 0, 0);
        }

    // ---- epilogue: bias + relu + per-graph max over nodes + atomicMax ----
    const int nb    = blockIdx.x * 64;
    const int gbase = batch[nb];                       // uniform
    const int glast = batch[nb + 63];                  // uniform
    const int idx   = batch[nb + T * 16 + m] - gbase;  // 0 or 1

    float v[16];
    #pragma unroll
    for (int cc = 0; cc < 4; ++cc) {
        const f32x4 b4 = *(const f32x4*)(bias + (c0 + cc) * 16 + q * 4);
        #pragma unroll
        for (int j = 0; j < 4; ++j)
            v[cc * 4 + j] = fmaxf(acc[cc][j] + b4[j], 0.f);
    }

    // slot 0 (graph gbase)
    {
        float r[16];
        #pragma unroll
        for (int k = 0; k < 16; ++k) r[k] = (idx == 0) ? v[k] : 0.f;
        #pragma unroll
        for (int msk = 1; msk <= 8; msk <<= 1)
            #pragma unroll
            for (int k = 0; k < 16; ++k)
                r[k] = fmaxf(r[k], __shfl_xor(r[k], msk));
        if (m == 0) {
            #pragma unroll
            for (int cc = 0; cc < 4; ++cc)
                #pragma unroll
                for (int j = 0; j < 4; ++j)
                    atomicMax(pool + (size_t)gbase * HDIM + (c0 + cc) * 16 + q * 4 + j,
                              __builtin_bit_cast(int, r[cc * 4 + j]));
        }
    }
    // slot 1 (graph gbase+1), only for boundary blocks
    if (glast != gbase) {
        float r[16];
        #pragma unroll
        for (int k = 0; k < 16; ++k) r[k] = (idx == 1) ? v[k] : 0.f;
        #pragma unroll
        for (int msk = 1; msk <= 8; msk <<= 1)
            #pragma unroll
            for (int k = 0; k < 16; ++k)
                r[k] = fmaxf(r[k], __shfl_xor(r[k], msk));
        if (m == 0) {
            #pragma unroll
            for (int cc = 0; cc < 4; ++cc)
                #pragma unroll
                for (int j = 0; j < 4; ++j)
                    atomicMax(pool + (size_t)(gbase + 1) * HDIM + (c0 + cc) * 16 + q * 4 + j,
                              __builtin_bit_cast(int, r[cc * 4 + j]));
        }
    }
}

// ---------------- f32 register-blocked GEMM (FF head only, tiny) ----------------
template<int K, int NC, bool OUT_RELU_BIAS>
__global__ __launch_bounds__(256) void k_gemm(
    const float* __restrict__ in, const float* __restrict__ W,
    const float* __restrict__ out_bias, float* __restrict__ out0, int M)
{
    constexpr int BK = 32;
    constexpr int TC = NC / 8;
    constexpr int TR = 256 / TC;
    constexpr int ROWS = TR * 8;
    constexpr int XST = ROWS + 4;

    __shared__ float xs[BK][XST];
    __shared__ float ws[BK][NC];

    const int tid = threadIdx.x;
    const int tc  = tid % TC;
    const int tr  = tid / TC;
    const int row0 = blockIdx.x * ROWS;

    float acc[8][8];
    #pragma unroll
    for (int i = 0; i < 8; ++i)
        #pragma unroll
        for (int j = 0; j < 8; ++j) acc[i][j] = 0.f;

    for (int k0 = 0; k0 < K; k0 += BK) {
        {
            constexpr int TASKS = BK * NC / 4;
            #pragma unroll
            for (int it = 0; it < TASKS / 256; ++it) {
                int t  = it * 256 + tid;
                int wk = t / (NC / 4);
                int wc = (t % (NC / 4)) * 4;
                *(float4*)(&ws[wk][wc]) = *(const float4*)(W + (size_t)(k0 + wk) * NC + wc);
            }
        }
        {
            constexpr int TASKS = ROWS * BK / 4;
            #pragma unroll
            for (int it = 0; it < TASKS / 256; ++it) {
                int t   = it * 256 + tid;
                int r   = t / (BK / 4);
                int kq  = (t % (BK / 4)) * 4;
                float4 x4 = *(const float4*)(in + (size_t)(row0 + r) * K + k0 + kq);
                xs[kq + 0][r] = x4.x; xs[kq + 1][r] = x4.y;
                xs[kq + 2][r] = x4.z; xs[kq + 3][r] = x4.w;
            }
        }
        __syncthreads();
        #pragma unroll 8
        for (int kk = 0; kk < BK; ++kk) {
            float a[8], b[8];
            #pragma unroll
            for (int i = 0; i < 8; ++i) a[i] = xs[kk][tr * 8 + i];
            #pragma unroll
            for (int j = 0; j < 8; ++j) b[j] = ws[kk][tc * 8 + j];
            #pragma unroll
            for (int i = 0; i < 8; ++i)
                #pragma unroll
                for (int j = 0; j < 8; ++j)
                    acc[i][j] = fmaf(a[i], b[j], acc[i][j]);
        }
        __syncthreads();
    }

    #pragma unroll
    for (int i = 0; i < 8; ++i) {
        const int row = row0 + tr * 8 + i;
        #pragma unroll
        for (int jq = 0; jq < 2; ++jq) {
            const int col = tc * 8 + jq * 4;
            float4 v;
            v.x = acc[i][jq * 4 + 0]; v.y = acc[i][jq * 4 + 1];
            v.z = acc[i][jq * 4 + 2]; v.w = acc[i][jq * 4 + 3];
            if constexpr (OUT_RELU_BIAS) {
                const float4 bb = *(const float4*)(out_bias + col);
                v.x = fmaxf(v.x + bb.x, 0.f); v.y = fmaxf(v.y + bb.y, 0.f);
                v.z = fmaxf(v.z + bb.z, 0.f); v.w = fmaxf(v.w + bb.w, 0.f);
            }
            *(float4*)(out0 + (size_t)row * NC + col) = v;
        }
    }
}

extern "C" void kernel_launch(void* const* d_in, const int* in_sizes, int n_in,
                              void* d_out, int out_size, void* d_ws, size_t ws_size,
                              hipStream_t stream) {
    const float* x    = (const float*)d_in[0];
    const int*   ei   = (const int*)d_in[1];
    const int*   batch= (const int*)d_in[2];
    const float* W0   = (const float*)d_in[3];
    const float* b0   = (const float*)d_in[4];
    const float* W1   = (const float*)d_in[5];
    const float* b1   = (const float*)d_in[6];
    const float* Wf0  = (const float*)d_in[7];
    const float* bf0  = (const float*)d_in[8];
    const float* Wf1  = (const float*)d_in[9];
    const float* bf1  = (const float*)d_in[10];
    float* out = (float*)d_out;

    const int* srcI = ei;
    const int* dstI = ei + NEDGES;

    constexpr int SCAN_NBLK = (NATOMS + 1023) / 1024;   // 391

    // workspace layout — ~293 MB (ws is ~499 MB per measured poison fill).
    //   rank aliases base+0 (dead after k_fill).
    //   xh at base+228000000 (128B-aligned rows), xt at base+280000000.
    char* base = (char*)d_ws;
    int*   rank      = (int*)(base + 0);                             // E ints
    unsigned short* aggB = (unsigned short*)(base + 102400000);      // N*128 bf16
    float* dinv      = (float*)(base + 204800000);                   // N f32
    int*   row_start = (int*)(base + 206400000);                     // N+1 ints
    int2*  csr_ev    = (int2*)(base + 208000064);                    // E int2
    int*   blockSums = (int*)(base + 220800064);                     // 512 ints
    float* pool      = (float*)(base + 220802112);                   // G*128 f32
    float* ff0       = (float*)(base + 222899264);                   // G*256 f32
    short* wf0       = (short*)(base + 227093568);                   // 24,576 B
    short* wf1       = (short*)(base + 227118144);                   // 32,768 B
    unsigned short* xh = (unsigned short*)(base + 228000000);        // N*64 bf16 = 51.2 MB
    unsigned short* xt = (unsigned short*)(base + 280000000);        // N*16 bf16 = 12.8 MB

    // 1) degree (+rank) -> scan (+dinv) -> atomic-free CSR fill
    hipMemsetAsync(row_start, 0, (size_t)(NATOMS + 1) * sizeof(int), stream);
    hipMemsetAsync(pool, 0, (size_t)NGRAPH * HDIM * sizeof(float), stream);  // relu identity
    k_degi<<<(NEDGES + 255) / 256, 256, 0, stream>>>(dstI, row_start, rank, NEDGES);
    k_scan1<<<SCAN_NBLK, 256, 0, stream>>>(row_start, blockSums, dinv, NATOMS);
    k_scan2<<<1, 512, 0, stream>>>(blockSums, SCAN_NBLK);
    k_scan3<<<SCAN_NBLK, 256, 0, stream>>>(row_start, blockSums, NATOMS, NEDGES);
    k_fill<<<(NEDGES + 255) / 256, 256, 0, stream>>>(srcI, dstI, row_start, rank,
                                                     csr_ev, dinv, NEDGES);

    // 2) pack weights (W0 augmented: k=78 row carries b0) + pack x to split bf16
    k_packw<3, F_INN, true><<<8 * 3, 64, 0, stream>>>(W0, b0, wf0);
    k_packw<4, HDIM, false><<<8 * 4, 64, 0, stream>>>(W1, nullptr, wf1);
    k_packx<<<(NATOMS * 10 + 255) / 256, 256, 0, stream>>>(x, xh, xt);

    // 3) layer 0 FUSED: gather(78-dim, split layout) + GEMM + bias + relu -> aggB
    k_fused0<<<NATOMS / 32, 256, 0, stream>>>(xh, xt, wf0, row_start, csr_ev, dinv,
                                              (short*)aggB);

    // 4) layer 1 FUSED: gather(128-dim over aggB) + GEMM + b1 + relu + max-pool
    k_fused1<<<NATOMS / 64, 512, 0, stream>>>(aggB, wf1, row_start, csr_ev,
                                              dinv, b1, batch, (int*)pool);

    // 5) FF head (f32, tiny)
    k_gemm<HDIM, FF0D, true><<<NGRAPH / 64, 256, 0, stream>>>(pool, Wf0, bf0, ff0, NGRAPH);
    k_gemm<FF0D, FF1D, true><<<NGRAPH / 128, 256, 0, stream>>>(ff0, Wf1, bf1, out, NGRAPH);
}